// Round 1
// 175.308 us; speedup vs baseline: 1.0530x; 1.0530x over previous
//
#include <hip/hip_runtime.h>
#include <hip/hip_bf16.h>

// out = x @ (W + 16*(M@N))^T + b  where M(1024x8), N(8x1024) are folded TT cores.
// Pipeline: prep (build Weff bf16 + cast x->bf16, one launch) ->
// bf16 MFMA GEMM. New: 256x128 tile, 8 waves, 3-deep cyclic LDS pipeline with
// counted vmcnt(6) (T3+T4), raw s_barrier, setprio (T5), XCD swizzle (T1).

#define D_DIM 1024
#define BS_ROWS 16384
#define ALPHA_F 16.0f
#define BM 128
#define BN 128

using bf16   = __bf16;
using bf16x8 = __attribute__((ext_vector_type(8))) __bf16;
using bf16x4 = __attribute__((ext_vector_type(4))) __bf16;
using f32x4  = __attribute__((ext_vector_type(4))) float;

#define GPTR(p) (const __attribute__((address_space(1))) void*)(p)
#define SPTR(p) (__attribute__((address_space(3))) void*)(p)

// ---- Kernel A: fused prep (unchanged, proven).
// Blocks [0,1024): Weff[o][d] = bf16(W[o][d] + 16*(M@N)[d][o]), o = blockIdx.
// Blocks [1024,9216): cast x chunk to bf16.
__global__ __launch_bounds__(256) void prep_kernel(
    const float* __restrict__ X,
    const float* __restrict__ W,
    const float* __restrict__ c0, const float* __restrict__ c1,
    const float* __restrict__ c2, const float* __restrict__ c3,
    const float* __restrict__ c4, const float* __restrict__ c5,
    bf16* __restrict__ Weff, bf16* __restrict__ Xb)
{
    __shared__ float t2[1024];    // [i2*8+i1][p2] : 128 x 8  (i2 in [0,16))
    __shared__ float Msh[8192];   // [d][p3]
    const int tid = threadIdx.x;

    if (blockIdx.x >= 1024) {
        // cast: 2048 elements per block, 8 per thread
        size_t i = ((size_t)(blockIdx.x - 1024) * 256 + tid) * 8;
        f32x4 a = *(const f32x4*)&X[i];
        f32x4 b = *(const f32x4*)&X[i + 4];
        bf16x8 v;
        v[0] = (bf16)a[0]; v[1] = (bf16)a[1]; v[2] = (bf16)a[2]; v[3] = (bf16)a[3];
        v[4] = (bf16)b[0]; v[5] = (bf16)b[1]; v[6] = (bf16)b[2]; v[7] = (bf16)b[3];
        *(bf16x8*)&Xb[i] = v;
        return;
    }

    const int o = blockIdx.x;
    // Phase 1: t2[(i2*8+i1)][p2] = sum_p1 c0[0,i1,p1]*c1[p1,i2,p2]
    for (int e = tid; e < 1024; e += 256) {
        int p2 = e & 7, i2i1 = e >> 3;
        int i1 = i2i1 & 7, i2 = i2i1 >> 3;
        float s = 0.f;
        for (int p1 = 0; p1 < 8; ++p1)
            s += c0[i1 * 8 + p1] * c1[p1 * 128 + i2 * 8 + p2];
        t2[e] = s;
    }
    __syncthreads();
    // Phase 2: M[d][p3] = sum_p2 t2[i2*8+i1][p2]*c2[p2,i3,p3], d=i3*128+i2*8+i1
    for (int e = tid; e < 8192; e += 256) {
        int p3 = e & 7, d = e >> 3;
        int i1 = d & 7, i2 = (d >> 3) & 15, i3 = d >> 7;
        float s = 0.f;
        for (int p2 = 0; p2 < 8; ++p2)
            s += t2[(i2 * 8 + i1) * 8 + p2] * c2[p2 * 64 + i3 * 8 + p3];
        Msh[e] = s;
    }

    // N column for this o
    int n1 = o >> 7, nn = o & 127, n2 = nn >> 3, n3 = nn & 7;
    float v[8];
    for (int p4 = 0; p4 < 8; ++p4) {
        float s = 0.f;
        for (int p5 = 0; p5 < 8; ++p5)
            s += c4[p4 * 128 + n2 * 8 + p5] * c5[p5 * 8 + n3];
        v[p4] = s;
    }
    float ncol[8];
    for (int r3 = 0; r3 < 8; ++r3) {
        float s = 0.f;
        for (int p4 = 0; p4 < 8; ++p4)
            s += c3[r3 * 64 + n1 * 8 + p4] * v[p4];
        ncol[r3] = s;
    }
    __syncthreads();

    int d0 = tid * 4;
    f32x4 w = *(const f32x4*)&W[o * D_DIM + d0];
    bf16x4 res;
    for (int k = 0; k < 4; ++k) {
        float acc = 0.f;
        for (int r = 0; r < 8; ++r)
            acc += Msh[(d0 + k) * 8 + r] * ncol[r];
        res[k] = (bf16)(w[k] + ALPHA_F * acc);
    }
    *(bf16x4*)&Weff[o * D_DIM + d0] = res;
}

// ---- Kernel B2: 16384x1024x1024 bf16 GEMM, 256x128 tile, BK=64 --------------
// 3-deep cyclic LDS pipeline: compute tile t from buf[t%3] while staging tile
// t+2 into buf[(t+2)%3] (its last reader finished at tile t-1's barrier ->
// race-free by buffer index). 6 global_load_lds per thread per tile; end-of-tile
// wait is vmcnt(6): tile t+1 landed, tile t+2's loads stay in flight across the
// barrier (counted-vmcnt, never drain-0 in the main loop).
// LDS rows are 128 B = 8 x 16B chunks, stored chunk = logical chunk ^ (row&7)
// (same proven conflict-free swizzle as before).
#define TBM 256
#define TBN 128
#define ABYTES (TBM * 128)            // 32 KB per A K-tile
#define BBYTES (TBN * 128)            // 16 KB per B K-tile
#define BUFB   (ABYTES + BBYTES)      // 48 KB per buffer
#define NBUFS  3
#define NTILES (D_DIM / 64)           // 16

__global__ __launch_bounds__(512, 2) void gemm_pipe_kernel(
    const bf16* __restrict__ Xb,
    const bf16* __restrict__ Weff,
    const float* __restrict__ bias,
    float* __restrict__ Out)
{
    extern __shared__ __attribute__((aligned(16))) char smem[];

    const int tid  = threadIdx.x;
    const int wave = tid >> 6, lane = tid & 63;

    // XCD-aware bijective swizzle: 512 blocks, 8 XCDs -> each XCD gets
    // 8 consecutive mtiles x all 8 ntiles (Xb slab reused 8x in its L2).
    const int bid   = blockIdx.x;
    const int slot  = (bid & 7) * 64 + (bid >> 3);
    const int mtile = slot >> 3;          // [0,64)
    const int ntile = slot & 7;           // [0,8)

    const int wr = wave >> 1, wc = wave & 1;   // 4M x 2N wave grid
    const int l15 = lane & 15, quad = lane >> 4;
    const int rsw = l15 & 7;

    // Staging addresses: issue covers 64 rows (8 rows/wave), lane l ->
    // row +(l>>3), stored chunk l&7, so global chunk = (l&7)^(l>>3).
    const int srow   = wave * 8 + (lane >> 3);
    const int gchunk = (lane & 7) ^ (lane >> 3);
    const bf16* asrc = Xb   + (size_t)(mtile * TBM + srow) * D_DIM + gchunk * 8;
    const bf16* bsrc = Weff + (size_t)(ntile * TBN + srow) * D_DIM + gchunk * 8;
    const int woff = wave * 1024;          // wave-uniform LDS byte offset

    auto STAGE = [&](int bo, int t) {
        const bf16* ap = asrc + t * 64;
        const bf16* bp = bsrc + t * 64;
        char* ad = smem + bo + woff;
        char* bd = smem + bo + ABYTES + woff;
#pragma unroll
        for (int j = 0; j < 4; ++j)
            __builtin_amdgcn_global_load_lds(GPTR(ap + (size_t)j * 64 * D_DIM),
                                             SPTR(ad + j * 8192), 16, 0, 0);
#pragma unroll
        for (int j = 0; j < 2; ++j)
            __builtin_amdgcn_global_load_lds(GPTR(bp + (size_t)j * 64 * D_DIM),
                                             SPTR(bd + j * 8192), 16, 0, 0);
    };

    f32x4 acc[4][4];
#pragma unroll
    for (int i = 0; i < 4; ++i)
#pragma unroll
        for (int j = 0; j < 4; ++j)
#pragma unroll
            for (int r = 0; r < 4; ++r) acc[i][j][r] = 0.f;

    auto COMPUTE = [&](int bo) {
        const bf16* Ab = (const bf16*)(smem + bo);
        const bf16* Bb = (const bf16*)(smem + bo + ABYTES);
#pragma unroll
        for (int kk = 0; kk < 2; ++kk) {
            const int sc = ((kk * 4 + quad) ^ rsw) * 8;  // swizzled chunk (elems)
            bf16x8 af[4], bfr[4];
#pragma unroll
            for (int i = 0; i < 4; ++i)
                af[i] = *(const bf16x8*)&Ab[(wr * 64 + i * 16 + l15) * 64 + sc];
#pragma unroll
            for (int j = 0; j < 4; ++j)
                bfr[j] = *(const bf16x8*)&Bb[(wc * 64 + j * 16 + l15) * 64 + sc];
            __builtin_amdgcn_s_setprio(1);
#pragma unroll
            for (int i = 0; i < 4; ++i)
#pragma unroll
                for (int j = 0; j < 4; ++j)
                    acc[i][j] = __builtin_amdgcn_mfma_f32_16x16x32_bf16(
                        af[i], bfr[j], acc[i][j], 0, 0, 0);
            __builtin_amdgcn_s_setprio(0);
        }
    };

    // Prologue: stage tiles 0,1; wait tile 0 (6 of 12 outstanding).
    STAGE(0, 0);
    STAGE(BUFB, 1);
    asm volatile("s_waitcnt vmcnt(6)" ::: "memory");
    __builtin_amdgcn_s_barrier();
    __builtin_amdgcn_sched_barrier(0);

    int bo = 0;
#pragma unroll
    for (int t = 0; t < NTILES - 2; ++t) {
        int bs = bo + 2 * BUFB; if (bs >= NBUFS * BUFB) bs -= NBUFS * BUFB;
        STAGE(bs, t + 2);
        COMPUTE(bo);
        // tile t+1 landed (oldest 6); tile t+2's 6 loads stay in flight.
        asm volatile("s_waitcnt vmcnt(6) lgkmcnt(0)" ::: "memory");
        __builtin_amdgcn_s_barrier();
        __builtin_amdgcn_sched_barrier(0);
        bo += BUFB; if (bo == NBUFS * BUFB) bo = 0;
    }
    // Tile NTILES-2: nothing left to stage; drain for the last tile.
    COMPUTE(bo);
    asm volatile("s_waitcnt vmcnt(0) lgkmcnt(0)" ::: "memory");
    __builtin_amdgcn_s_barrier();
    __builtin_amdgcn_sched_barrier(0);
    bo += BUFB; if (bo == NBUFS * BUFB) bo = 0;
    // Tile NTILES-1.
    COMPUTE(bo);

    // Epilogue: C/D layout col = lane&15, row = quad*4 + reg
    float bj[4];
#pragma unroll
    for (int j = 0; j < 4; ++j)
        bj[j] = bias[ntile * TBN + wc * 64 + j * 16 + l15];
#pragma unroll
    for (int i = 0; i < 4; ++i) {
        int row0 = mtile * TBM + wr * 64 + i * 16 + quad * 4;
#pragma unroll
        for (int r = 0; r < 4; ++r) {
            float* orow = Out + (size_t)(row0 + r) * D_DIM + ntile * TBN + wc * 64 + l15;
#pragma unroll
            for (int j = 0; j < 4; ++j)
                orow[j * 16] = acc[i][j][r] + bj[j];
        }
    }
}

// ---- Kernel B (previous best, kept as fallback if dynamic-LDS attr fails) ---
__global__ __launch_bounds__(256) void gemm_bb_kernel(
    const bf16* __restrict__ Xb,
    const bf16* __restrict__ Weff,
    const float* __restrict__ bias,
    float* __restrict__ Out)
{
    __shared__ __align__(16) bf16 As[BM][64];  // 16 KB
    __shared__ __align__(16) bf16 Bs[BN][64];  // 16 KB

    const int tid  = threadIdx.x;
    const int wave = tid >> 6, lane = tid & 63;
    const int mtile = blockIdx.x, ntile = blockIdx.y;
    const int wr = wave >> 1, wc = wave & 1;
    const int l15 = lane & 15, quad = lane >> 4;

    const int srow = wave * 32 + (lane >> 3);
    const int gchunk = (lane & 7) ^ (lane >> 3);
    const bf16* asrc = Xb   + (size_t)(mtile * BM + srow) * D_DIM + gchunk * 8;
    const bf16* bsrc = Weff + (size_t)(ntile * BN + srow) * D_DIM + gchunk * 8;
    char* abase = (char*)&As[0][0] + wave * 4096;
    char* bbase = (char*)&Bs[0][0] + wave * 4096;

    const int rsw = l15 & 7;

    f32x4 acc[4][4];
    for (int i = 0; i < 4; ++i)
        for (int j = 0; j < 4; ++j)
            for (int r = 0; r < 4; ++r) acc[i][j][r] = 0.f;

    for (int kt = 0; kt < D_DIM / 64; ++kt) {
        const int ko = kt * 64;
        for (int j = 0; j < 4; ++j) {
            __builtin_amdgcn_global_load_lds(GPTR(asrc + (size_t)j * 8 * D_DIM + ko),
                                             SPTR(abase + j * 1024), 16, 0, 0);
            __builtin_amdgcn_global_load_lds(GPTR(bsrc + (size_t)j * 8 * D_DIM + ko),
                                             SPTR(bbase + j * 1024), 16, 0, 0);
        }

        __syncthreads();

        for (int kk = 0; kk < 2; ++kk) {
            const int lc = kk * 4 + quad;
            const int sc = (lc ^ rsw) * 8;
            bf16x8 af[4], bfr[4];
            for (int i = 0; i < 4; ++i)
                af[i] = *(const bf16x8*)&As[wr * 64 + i * 16 + l15][sc];
            for (int j = 0; j < 4; ++j)
                bfr[j] = *(const bf16x8*)&Bs[wc * 64 + j * 16 + l15][sc];
            for (int i = 0; i < 4; ++i)
                for (int j = 0; j < 4; ++j)
                    acc[i][j] = __builtin_amdgcn_mfma_f32_16x16x32_bf16(
                        af[i], bfr[j], acc[i][j], 0, 0, 0);
        }

        __syncthreads();
    }

    float bj[4];
    for (int j = 0; j < 4; ++j)
        bj[j] = bias[ntile * BN + wc * 64 + j * 16 + l15];
    for (int i = 0; i < 4; ++i) {
        int row0 = mtile * BM + wr * 64 + i * 16 + quad * 4;
        for (int r = 0; r < 4; ++r) {
            float* orow = Out + (size_t)(row0 + r) * D_DIM + ntile * BN + wc * 64 + l15;
            for (int j = 0; j < 4; ++j)
                orow[j * 16] = acc[i][j][r] + bj[j];
        }
    }
}

// ---- Fallback GEMM (fp32 A staged via VALU convert) — used if ws too small --
__global__ __launch_bounds__(256) void gemm_bias_kernel(
    const float* __restrict__ X,
    const bf16* __restrict__ Weff,
    const float* __restrict__ bias,
    float* __restrict__ Out)
{
    __shared__ __align__(16) bf16 As[BM][32];
    __shared__ __align__(16) bf16 Bs[BN][32];

    const int tid  = threadIdx.x;
    const int wave = tid >> 6, lane = tid & 63;
    const int mtile = blockIdx.x, ntile = blockIdx.y;
    const int wr = wave >> 1, wc = wave & 1;
    const int l15 = lane & 15, quad = lane >> 4;

    const int ar = tid >> 1, ah = tid & 1;
    const float* xsrc = X + (size_t)(mtile * BM + ar) * D_DIM + ah * 16;
    bf16* adst = &As[ar][ah * 16];

    const bf16* bsrc0 = Weff + (size_t)(ntile * BN + wave * 32 + (lane >> 2)) * D_DIM
                        + (lane & 3) * 8;
    const bf16* bsrc1 = bsrc0 + 16 * D_DIM;
    char* bbase = (char*)&Bs[0][0];
    void* bdst0 = bbase + wave * 2048;
    void* bdst1 = bbase + wave * 2048 + 1024;

    f32x4 acc[4][4];
    for (int i = 0; i < 4; ++i)
        for (int j = 0; j < 4; ++j)
            for (int r = 0; r < 4; ++r) acc[i][j][r] = 0.f;

    for (int kt = 0; kt < D_DIM / 32; ++kt) {
        __builtin_amdgcn_global_load_lds(GPTR(bsrc0 + kt * 32), SPTR(bdst0), 16, 0, 0);
        __builtin_amdgcn_global_load_lds(GPTR(bsrc1 + kt * 32), SPTR(bdst1), 16, 0, 0);

        const f32x4* xp = (const f32x4*)(xsrc + kt * 32);
        f32x4 f0 = xp[0], f1 = xp[1], f2 = xp[2], f3 = xp[3];
        bf16x8 p0, p1;
        p0[0] = (bf16)f0[0]; p0[1] = (bf16)f0[1]; p0[2] = (bf16)f0[2]; p0[3] = (bf16)f0[3];
        p0[4] = (bf16)f1[0]; p0[5] = (bf16)f1[1]; p0[6] = (bf16)f1[2]; p0[7] = (bf16)f1[3];
        p1[0] = (bf16)f2[0]; p1[1] = (bf16)f2[1]; p1[2] = (bf16)f2[2]; p1[3] = (bf16)f2[3];
        p1[4] = (bf16)f3[0]; p1[5] = (bf16)f3[1]; p1[6] = (bf16)f3[2]; p1[7] = (bf16)f3[3];
        *(bf16x8*)adst = p0;
        *(bf16x8*)(adst + 8) = p1;

        __syncthreads();

        bf16x8 af[4], bfr[4];
        for (int i = 0; i < 4; ++i)
            af[i] = *(const bf16x8*)&As[wr * 64 + i * 16 + l15][quad * 8];
        for (int j = 0; j < 4; ++j)
            bfr[j] = *(const bf16x8*)&Bs[wc * 64 + j * 16 + l15][quad * 8];
        for (int i = 0; i < 4; ++i)
            for (int j = 0; j < 4; ++j)
                acc[i][j] = __builtin_amdgcn_mfma_f32_16x16x32_bf16(
                    af[i], bfr[j], acc[i][j], 0, 0, 0);

        __syncthreads();
    }

    float bj[4];
    for (int j = 0; j < 4; ++j)
        bj[j] = bias[ntile * BN + wc * 64 + j * 16 + l15];
    for (int i = 0; i < 4; ++i) {
        int row0 = mtile * BM + wr * 64 + i * 16 + quad * 4;
        for (int r = 0; r < 4; ++r) {
            float* orow = Out + (size_t)(row0 + r) * D_DIM + ntile * BN + wc * 64 + l15;
            for (int j = 0; j < 4; ++j)
                orow[j * 16] = acc[i][j][r] + bj[j];
        }
    }
}

// Standalone Weff builder for fallback path
__global__ __launch_bounds__(256) void build_weff_fused_kernel(
    const float* __restrict__ W,
    const float* __restrict__ c0, const float* __restrict__ c1,
    const float* __restrict__ c2, const float* __restrict__ c3,
    const float* __restrict__ c4, const float* __restrict__ c5,
    bf16* __restrict__ Weff)
{
    __shared__ float t2[1024];
    __shared__ float Msh[8192];
    const int tid = threadIdx.x;
    const int o = blockIdx.x;

    for (int e = tid; e < 1024; e += 256) {
        int p2 = e & 7, i2i1 = e >> 3;
        int i1 = i2i1 & 7, i2 = i2i1 >> 3;
        float s = 0.f;
        for (int p1 = 0; p1 < 8; ++p1)
            s += c0[i1 * 8 + p1] * c1[p1 * 128 + i2 * 8 + p2];
        t2[e] = s;
    }
    __syncthreads();
    for (int e = tid; e < 8192; e += 256) {
        int p3 = e & 7, d = e >> 3;
        int i1 = d & 7, i2 = (d >> 3) & 15, i3 = d >> 7;
        float s = 0.f;
        for (int p2 = 0; p2 < 8; ++p2)
            s += t2[(i2 * 8 + i1) * 8 + p2] * c2[p2 * 64 + i3 * 8 + p3];
        Msh[e] = s;
    }
    int n1 = o >> 7, nn = o & 127, n2 = nn >> 3, n3 = nn & 7;
    float v[8];
    for (int p4 = 0; p4 < 8; ++p4) {
        float s = 0.f;
        for (int p5 = 0; p5 < 8; ++p5)
            s += c4[p4 * 128 + n2 * 8 + p5] * c5[p5 * 8 + n3];
        v[p4] = s;
    }
    float ncol[8];
    for (int r3 = 0; r3 < 8; ++r3) {
        float s = 0.f;
        for (int p4 = 0; p4 < 8; ++p4)
            s += c3[r3 * 64 + n1 * 8 + p4] * v[p4];
        ncol[r3] = s;
    }
    __syncthreads();

    int d0 = tid * 4;
    f32x4 w = *(const f32x4*)&W[o * D_DIM + d0];
    bf16x4 res;
    for (int k = 0; k < 4; ++k) {
        float acc = 0.f;
        for (int r = 0; r < 8; ++r)
            acc += Msh[(d0 + k) * 8 + r] * ncol[r];
        res[k] = (bf16)(w[k] + ALPHA_F * acc);
    }
    *(bf16x4*)&Weff[o * D_DIM + d0] = res;
}

extern "C" void kernel_launch(void* const* d_in, const int* in_sizes, int n_in,
                              void* d_out, int out_size, void* d_ws, size_t ws_size,
                              hipStream_t stream) {
    const float* x  = (const float*)d_in[0];
    const float* W  = (const float*)d_in[1];
    const float* b  = (const float*)d_in[2];
    const float* c0 = (const float*)d_in[3];
    const float* c1 = (const float*)d_in[4];
    const float* c2 = (const float*)d_in[5];
    const float* c3 = (const float*)d_in[6];
    const float* c4 = (const float*)d_in[7];
    const float* c5 = (const float*)d_in[8];
    float* out = (float*)d_out;

    // Workspace: Weff bf16 2MB @0 | Xb 32MB @4MB
    char* ws = (char*)d_ws;
    bf16* Weff = (bf16*)ws;
    bf16* Xb   = (bf16*)(ws + 4u * 1024u * 1024u);
    const size_t need = 4u * 1024u * 1024u + (size_t)BS_ROWS * D_DIM * 2u;

    // One-time: raise dynamic-LDS cap for the pipelined GEMM (144 KB).
    static int smem_ok = -1;
    if (smem_ok < 0) {
        hipError_t e = hipFuncSetAttribute((const void*)gemm_pipe_kernel,
                                           hipFuncAttributeMaxDynamicSharedMemorySize,
                                           NBUFS * BUFB);
        smem_ok = (e == hipSuccess) ? 1 : 0;
    }

    if (ws_size >= need) {
        prep_kernel<<<1024 + 8192, 256, 0, stream>>>(x, W, c0, c1, c2, c3, c4, c5,
                                                     Weff, Xb);
        if (smem_ok) {
            gemm_pipe_kernel<<<dim3(512), 512, NBUFS * BUFB, stream>>>(Xb, Weff, b, out);
        } else {
            dim3 grid(BS_ROWS / BM, D_DIM / BN);
            gemm_bb_kernel<<<grid, 256, 0, stream>>>(Xb, Weff, b, out);
        }
    } else {
        build_weff_fused_kernel<<<D_DIM, 256, 0, stream>>>(W, c0, c1, c2, c3, c4, c5, Weff);
        dim3 grid(BS_ROWS / BM, D_DIM / BN);
        gemm_bias_kernel<<<grid, 256, 0, stream>>>(x, Weff, b, out);
    }
}